// Round 4
// baseline (1251.356 us; speedup 1.0000x reference)
//
#include <hip/hip_runtime.h>
#include <cstddef>

// ---------------------------------------------------------------------------
// MultiHead attention, B=4 T=1024 D=1024 N=16 DH=64, SCALE=32, causal + bias.
// Round 4: MEASUREMENT ROUND. Kernels identical to round 3, but proj/attn/out
// bodies repeat REP=8x in-kernel (idempotent) so each dispatch exceeds the
// harness's 155us fill dispatches and surfaces in rocprof top-5 with full
// counters. True per-kernel cost = dur_us / 8.
// ---------------------------------------------------------------------------

#define REP 8

typedef __attribute__((ext_vector_type(8))) short bf16x8;
typedef __attribute__((ext_vector_type(4))) float f32x4;

#define MFMA16(a, b, c) __builtin_amdgcn_mfma_f32_16x16x32_bf16(a, b, c, 0, 0, 0)

__device__ __forceinline__ short f2bf(float f) {
  union { float f; unsigned int i; } v; v.f = f;
  unsigned int r = v.i + 0x7FFFu + ((v.i >> 16) & 1u);  // RNE
  return (short)(r >> 16);
}

__device__ __forceinline__ void gload_lds16(const void* g, void* l) {
  __builtin_amdgcn_global_load_lds(
      (const __attribute__((address_space(1))) void*)g,
      (__attribute__((address_space(3))) void*)l, 16, 0, 0);
}

// ---------------------------------------------------------------------------
// Fused f32 -> bf16 conversion for all 7 tensors (one launch). Not amplified.
// ---------------------------------------------------------------------------
__global__ __launch_bounds__(256) void cvt_all(
    const float* __restrict__ q, const float* __restrict__ k, const float* __restrict__ v,
    const float* __restrict__ wq, const float* __restrict__ wk,
    const float* __restrict__ wv, const float* __restrict__ wo,
    short* __restrict__ qb, short* __restrict__ kb, short* __restrict__ vb,
    short* __restrict__ wqb, short* __restrict__ wkb,
    short* __restrict__ wvb, short* __restrict__ wob) {
  const int total = 16 * 1048576 / 4;  // vec4 count
  int stride = gridDim.x * blockDim.x;
  for (int i = blockIdx.x * blockDim.x + threadIdx.x; i < total; i += stride) {
    int e = i * 4;
    int chunk = e >> 20;
    const float* s;
    short* d;
    int off;
    if (chunk < 12) {
      if (chunk < 4)      { s = q; d = qb; }
      else if (chunk < 8) { s = k; d = kb; }
      else                { s = v; d = vb; }
      off = e & (4 * 1048576 - 1);
    } else {
      int w = chunk - 12;
      if (w == 0)      { s = wq; d = wqb; }
      else if (w == 1) { s = wk; d = wkb; }
      else if (w == 2) { s = wv; d = wvb; }
      else             { s = wo; d = wob; }
      off = e & (1048576 - 1);
    }
    float4 x = *(const float4*)(s + off);
    short4 o;
    o.x = f2bf(x.x); o.y = f2bf(x.y); o.z = f2bf(x.z); o.w = f2bf(x.w);
    *(short4*)(d + off) = o;
  }
}

// ---------------------------------------------------------------------------
// Fused Q/K/V projection (256x64 tile, 4 waves). REP-amplified.
// ---------------------------------------------------------------------------
__global__ __launch_bounds__(256) void proj_qkv(
    const short* __restrict__ qA, const short* __restrict__ kA, const short* __restrict__ vA,
    const short* __restrict__ Wqb, const short* __restrict__ Wkb, const short* __restrict__ Wvb,
    const float* __restrict__ bq, const float* __restrict__ bk, const float* __restrict__ bv,
    short* __restrict__ Qh, short* __restrict__ Kh, short* __restrict__ Vth) {
  __shared__ short SMEM[256 * 64 + 64 * 64];  // As(32K) + Bs(8K); reused as Vt
  short* As = SMEM;
  short* Bs = SMEM + 256 * 64;

  const int m0 = blockIdx.x * 256;
  const int n0 = blockIdx.y * 64;
  const int z = blockIdx.z;

  const short *A, *W;
  const float* bias;
  if (z == 0)      { A = qA; W = Wqb; bias = bq; }
  else if (z == 1) { A = kA; W = Wkb; bias = bk; }
  else             { A = vA; W = Wvb; bias = bv; }

  const int tid = threadIdx.x;
  const int wid = tid >> 6, lane = tid & 63;
  const int fr = lane & 15, fq = lane >> 4;

  for (int rep = 0; rep < REP; ++rep) {
    __syncthreads();  // guard LDS reuse across reps
    f32x4 acc[4][4] = {};

    for (int kt = 0; kt < 16; ++kt) {
#pragma unroll
      for (int c = 0; c < 8; ++c) {
        int pbase = c * 4096 + wid * 1024;
        int pb = pbase + lane * 16;
        int lb = pb ^ (((pb >> 7) & 7) << 4);
        int grow = lb >> 7, gcol = (lb & 127) >> 1;
        gload_lds16(A + (size_t)(m0 + grow) * 1024 + kt * 64 + gcol, (char*)As + pbase);
      }
#pragma unroll
      for (int c = 0; c < 2; ++c) {
        int pbase = c * 4096 + wid * 1024;
        int pb = pbase + lane * 16;
        int lb = pb ^ (((pb >> 7) & 7) << 4);
        int grow = lb >> 7, gcol = (lb & 127) >> 1;
        gload_lds16(W + (size_t)(n0 + grow) * 1024 + kt * 64 + gcol, (char*)Bs + pbase);
      }
      __syncthreads();
#pragma unroll
      for (int kk = 0; kk < 2; ++kk) {
        bf16x8 af[4], bg[4];
        int cb = (fq * 8 + kk * 32) * 2;
#pragma unroll
        for (int m = 0; m < 4; ++m) {
          int r = wid * 64 + m * 16 + fr;
          af[m] = *(const bf16x8*)((const char*)As + (((r << 7) + cb) ^ ((r & 7) << 4)));
        }
#pragma unroll
        for (int n = 0; n < 4; ++n) {
          int r = n * 16 + fr;
          bg[n] = *(const bf16x8*)((const char*)Bs + (((r << 7) + cb) ^ ((r & 7) << 4)));
        }
#pragma unroll
        for (int m = 0; m < 4; ++m)
#pragma unroll
          for (int n = 0; n < 4; ++n)
            acc[m][n] = MFMA16(af[m], bg[n], acc[m][n]);
      }
      __syncthreads();
    }

    if (z < 2) {
      short* dst = (z == 0) ? Qh : Kh;
#pragma unroll
      for (int m = 0; m < 4; ++m)
#pragma unroll
        for (int n = 0; n < 4; ++n) {
          int col = n0 + n * 16 + fr;
          float bval = bias[col];
          int row0 = m0 + wid * 64 + m * 16 + fq * 4;
          int hh = col >> 6, dh = col & 63;
#pragma unroll
          for (int j = 0; j < 4; ++j) {
            int row = row0 + j;
            int bb = row >> 10, t = row & 1023;
            dst[(((size_t)(bb * 16 + hh)) * 1024 + t) * 64 + dh] = f2bf(acc[m][n][j] + bval);
          }
        }
    } else {
      short* Vt = SMEM;  // [64][264] shorts
#pragma unroll
      for (int m = 0; m < 4; ++m)
#pragma unroll
        for (int n = 0; n < 4; ++n) {
          int coll = n * 16 + fr;
          float bval = bias[n0 + coll];
          int rowl0 = wid * 64 + m * 16 + fq * 4;
#pragma unroll
          for (int j = 0; j < 4; ++j)
            Vt[coll * 264 + rowl0 + j] = f2bf(acc[m][n][j] + bval);
        }
      __syncthreads();
      const int bb = m0 >> 10, t0 = m0 & 1023;
#pragma unroll
      for (int it = 0; it < 8; ++it) {
        int qq = tid + it * 256;
        int rowl = qq >> 5, seg = qq & 31;
        bf16x8 vv = *(const bf16x8*)&Vt[rowl * 264 + seg * 8];
        int cg = n0 + rowl, hh = cg >> 6, dh = cg & 63;
        *(bf16x8*)&Vth[(((size_t)(bb * 16 + hh)) * 64 + dh) * 1024 + t0 + seg * 8] = vv;
      }
    }
  }
}

// ---------------------------------------------------------------------------
// Output projection (512 thr / 8 waves, 256x64 tile). REP-amplified.
// ---------------------------------------------------------------------------
__global__ __launch_bounds__(512) void gemm_out(const short* __restrict__ A,
                                                const short* __restrict__ W,
                                                const float* __restrict__ bias,
                                                float* __restrict__ C) {
  __shared__ short As[256 * 64];
  __shared__ short Bs[64 * 64];
  const int m0 = blockIdx.x * 256;
  const int n0 = blockIdx.y * 64;

  const int tid = threadIdx.x;
  const int wid = tid >> 6, lane = tid & 63;
  const int fr = lane & 15, fq = lane >> 4;

  for (int rep = 0; rep < REP; ++rep) {
    __syncthreads();
    f32x4 acc[2][4] = {};

    for (int kt = 0; kt < 16; ++kt) {
#pragma unroll
      for (int c = 0; c < 4; ++c) {
        int pbase = c * 8192 + wid * 1024;
        int pb = pbase + lane * 16;
        int lb = pb ^ (((pb >> 7) & 7) << 4);
        int grow = lb >> 7, gcol = (lb & 127) >> 1;
        gload_lds16(A + (size_t)(m0 + grow) * 1024 + kt * 64 + gcol, (char*)As + pbase);
      }
      {
        int pbase = wid * 1024;
        int pb = pbase + lane * 16;
        int lb = pb ^ (((pb >> 7) & 7) << 4);
        int grow = lb >> 7, gcol = (lb & 127) >> 1;
        gload_lds16(W + (size_t)(n0 + grow) * 1024 + kt * 64 + gcol, (char*)Bs + pbase);
      }
      __syncthreads();
#pragma unroll
      for (int kk = 0; kk < 2; ++kk) {
        bf16x8 af[2], bg[4];
        int cb = (fq * 8 + kk * 32) * 2;
#pragma unroll
        for (int m = 0; m < 2; ++m) {
          int r = wid * 32 + m * 16 + fr;
          af[m] = *(const bf16x8*)((const char*)As + (((r << 7) + cb) ^ ((r & 7) << 4)));
        }
#pragma unroll
        for (int n = 0; n < 4; ++n) {
          int r = n * 16 + fr;
          bg[n] = *(const bf16x8*)((const char*)Bs + (((r << 7) + cb) ^ ((r & 7) << 4)));
        }
#pragma unroll
        for (int m = 0; m < 2; ++m)
#pragma unroll
          for (int n = 0; n < 4; ++n)
            acc[m][n] = MFMA16(af[m], bg[n], acc[m][n]);
      }
      __syncthreads();
    }

#pragma unroll
    for (int m = 0; m < 2; ++m)
#pragma unroll
      for (int n = 0; n < 4; ++n) {
        int col = n0 + n * 16 + fr;
        float bval = bias[col];
        int row0 = m0 + wid * 32 + m * 16 + fq * 4;
#pragma unroll
        for (int j = 0; j < 4; ++j)
          C[(size_t)(row0 + j) * 1024 + col] = acc[m][n][j] + bval;
      }
  }
}

// ---------------------------------------------------------------------------
// Flash attention per head (round-3 structure). REP-amplified.
// ---------------------------------------------------------------------------
__global__ __launch_bounds__(256) void attn_kernel(
    const short* __restrict__ Qh, const short* __restrict__ Kh,
    const short* __restrict__ Vth, const float* __restrict__ Wb,
    const float* __restrict__ mask, short* __restrict__ Aout) {
  __shared__ short Ks[2][64 * 64];
  __shared__ short Vs[2][64 * 64];
  __shared__ short Ps[4][16 * 80];

  const int tid = threadIdx.x;
  const int wid = tid >> 6, lane = tid & 63;
  const int fr = lane & 15, fq = lane >> 4;
  const int h = blockIdx.y, b = h >> 4;
  const int qi = (int)gridDim.x - 1 - (int)blockIdx.x;  // heavy tiles first
  const int q0 = qi * 64;
  const int qrow0 = q0 + wid * 16;

  const short* qbase = Qh + ((size_t)h * 1024 + qrow0 + fr) * 64 + fq * 8;
  bf16x8 qf0 = *(const bf16x8*)qbase;
  bf16x8 qf1 = *(const bf16x8*)(qbase + 32);

  auto stage = [&](int buf, int k0) {
#pragma unroll
    for (int c = 0; c < 2; ++c) {
      int pbase = c * 4096 + wid * 1024;
      int pb = pbase + lane * 16;
      int lb = pb ^ (((pb >> 7) & 7) << 4);
      int grow = lb >> 7, gcol = (lb & 127) >> 1;
      gload_lds16(Kh + ((size_t)h * 1024 + k0 + grow) * 64 + gcol, (char*)Ks[buf] + pbase);
      gload_lds16(Vth + ((size_t)h * 64 + grow) * 1024 + k0 + gcol, (char*)Vs[buf] + pbase);
    }
  };

  const float* wbase = Wb + (size_t)h * 1024 * 1024;
  auto load_bias = [&](float (&bv)[4][4], int k0) {
#pragma unroll
    for (int nt = 0; nt < 4; ++nt)
#pragma unroll
      for (int j = 0; j < 4; ++j)
        bv[nt][j] = wbase[(size_t)(qrow0 + fq * 4 + j) * 1024 + (k0 + nt * 16 + fr)];
  };

  for (int rep = 0; rep < REP; ++rep) {
    f32x4 o_acc[4] = {};
    float m_run[4], l_run[4];
#pragma unroll
    for (int j = 0; j < 4; ++j) { m_run[j] = -3.0e38f; l_run[j] = 0.f; }

    float bias_cur[4][4], bias_nxt[4][4];
    __syncthreads();  // guard Ks/Vs reuse across reps
    stage(0, 0);
    load_bias(bias_cur, 0);
    __syncthreads();
    int cur = 0;

    for (int kt = 0; kt <= qi; ++kt) {
      const int k0 = kt * 64;
      if (kt < qi) {
        stage(cur ^ 1, k0 + 64);
        load_bias(bias_nxt, k0 + 64);
      }
      float mk[4];
#pragma unroll
      for (int nt = 0; nt < 4; ++nt)
        mk[nt] = mask[b * 1024 + k0 + nt * 16 + fr];

      f32x4 s_acc[4] = {};
#pragma unroll
      for (int kk = 0; kk < 2; ++kk)
#pragma unroll
        for (int nt = 0; nt < 4; ++nt) {
          int r = nt * 16 + fr;
          int cb = (fq * 8 + kk * 32) * 2;
          bf16x8 kf = *(const bf16x8*)((const char*)Ks[cur] + (((r << 7) + cb) ^ ((r & 7) << 4)));
          s_acc[nt] = MFMA16(kk == 0 ? qf0 : qf1, kf, s_acc[nt]);
        }

      float p[4][4];
#pragma unroll
      for (int j = 0; j < 4; ++j) {
        const int rq = qrow0 + fq * 4 + j;
        float mx = -3.0e38f;
#pragma unroll
        for (int nt = 0; nt < 4; ++nt) {
          int ck = k0 + nt * 16 + fr;
          float s = (s_acc[nt][j] + bias_cur[nt][j]) * 0.03125f
                    - (1.0f - mk[nt]) * 3.125e8f;
          if (ck > rq) s = -3.0e38f;
          p[nt][j] = s;
          mx = fmaxf(mx, s);
        }
#pragma unroll
        for (int d = 1; d < 16; d <<= 1) mx = fmaxf(mx, __shfl_xor(mx, d, 16));
        float mnew = fmaxf(m_run[j], mx);
        float corr = __expf(m_run[j] - mnew);
        m_run[j] = mnew;
        float rsum = 0.f;
#pragma unroll
        for (int nt = 0; nt < 4; ++nt) {
          float e = __expf(p[nt][j] - mnew);
          p[nt][j] = e;
          rsum += e;
        }
#pragma unroll
        for (int d = 1; d < 16; d <<= 1) rsum += __shfl_xor(rsum, d, 16);
        l_run[j] = l_run[j] * corr + rsum;
#pragma unroll
        for (int nt = 0; nt < 4; ++nt) o_acc[nt][j] *= corr;
      }

#pragma unroll
      for (int nt = 0; nt < 4; ++nt)
#pragma unroll
        for (int j = 0; j < 4; ++j)
          Ps[wid][(fq * 4 + j) * 80 + nt * 16 + fr] = f2bf(p[nt][j]);
      asm volatile("s_waitcnt lgkmcnt(0)" ::: "memory");
      bf16x8 pf0 = *(const bf16x8*)&Ps[wid][fr * 80 + fq * 8];
      bf16x8 pf1 = *(const bf16x8*)&Ps[wid][fr * 80 + fq * 8 + 32];

#pragma unroll
      for (int kk = 0; kk < 2; ++kk)
#pragma unroll
        for (int nt = 0; nt < 4; ++nt) {
          int r = nt * 16 + fr;
          int cb = (fq * 8 + kk * 32) * 2;
          bf16x8 vf = *(const bf16x8*)((const char*)Vs[cur] + (((r << 7) + cb) ^ ((r & 7) << 4)));
          o_acc[nt] = MFMA16(kk == 0 ? pf0 : pf1, vf, o_acc[nt]);
        }
      __syncthreads();
      if (kt < qi) {
#pragma unroll
        for (int nt = 0; nt < 4; ++nt)
#pragma unroll
          for (int j = 0; j < 4; ++j) bias_cur[nt][j] = bias_nxt[nt][j];
      }
      cur ^= 1;
    }

#pragma unroll
    for (int nt = 0; nt < 4; ++nt)
#pragma unroll
      for (int j = 0; j < 4; ++j) {
        int row = b * 1024 + q0 + wid * 16 + fq * 4 + j;
        int col = (h & 15) * 64 + nt * 16 + fr;
        Aout[(size_t)row * 1024 + col] = f2bf(o_acc[nt][j] / l_run[j]);
      }
  }
}

// ---------------------------------------------------------------------------
extern "C" void kernel_launch(void* const* d_in, const int* in_sizes, int n_in,
                              void* d_out, int out_size, void* d_ws, size_t ws_size,
                              hipStream_t stream) {
  const float* query = (const float*)d_in[0];
  const float* key   = (const float*)d_in[1];
  const float* value = (const float*)d_in[2];
  const float* mask  = (const float*)d_in[3];
  const float* wts   = (const float*)d_in[4];
  const float* Wq    = (const float*)d_in[5];
  const float* bq    = (const float*)d_in[6];
  const float* Wk    = (const float*)d_in[7];
  const float* bk    = (const float*)d_in[8];
  const float* Wv    = (const float*)d_in[9];
  const float* bv    = (const float*)d_in[10];
  const float* Wo    = (const float*)d_in[11];
  const float* bo    = (const float*)d_in[12];

  char* ws = (char*)d_ws;
  const size_t MB = 1u << 20;
  short* qbf = (short*)(ws + 0);        // 8 MB  (reused as attn out)
  short* kbf = (short*)(ws + 8 * MB);   // 8 MB
  short* vbf = (short*)(ws + 16 * MB);  // 8 MB
  short* Wqb = (short*)(ws + 24 * MB);  // 2 MB
  short* Wkb = (short*)(ws + 26 * MB);
  short* Wvb = (short*)(ws + 28 * MB);
  short* Wob = (short*)(ws + 30 * MB);
  short* Qh  = (short*)(ws + 32 * MB);  // 8 MB [B,N,T,DH]
  short* Kh  = (short*)(ws + 40 * MB);  // 8 MB [B,N,T,DH]
  short* Vth = (short*)(ws + 48 * MB);  // 8 MB [B,N,DH,T]
  short* attnb = qbf;                   // alias: qbf dead after proj_qkv

  cvt_all<<<dim3(2048), dim3(256), 0, stream>>>(query, key, value, Wq, Wk, Wv, Wo,
                                                qbf, kbf, vbf, Wqb, Wkb, Wvb, Wob);
  proj_qkv<<<dim3(16, 16, 3), dim3(256), 0, stream>>>(qbf, kbf, vbf, Wqb, Wkb, Wvb,
                                                      bq, bk, bv, Qh, Kh, Vth);
  attn_kernel<<<dim3(16, 64), dim3(256), 0, stream>>>(Qh, Kh, Vth, wts, mask, attnb);
  gemm_out<<<dim3(16, 16), dim3(512), 0, stream>>>(attnb, Wob, bo, (float*)d_out);
}

// Round 5
// 220.424 us; speedup vs baseline: 5.6770x; 5.6770x over previous
//
#include <hip/hip_runtime.h>
#include <cstddef>

// ---------------------------------------------------------------------------
// MultiHead attention, B=4 T=1024 D=1024 N=16 DH=64, SCALE=32, causal + bias.
// Round 5: attn barrier-free — K/V read direct from L2 (no LDS staging, no
// __syncthreads), Ps stride 84 (conflict-free), diag-only causal mask.
// ---------------------------------------------------------------------------

typedef __attribute__((ext_vector_type(8))) short bf16x8;
typedef __attribute__((ext_vector_type(4))) float f32x4;

#define MFMA16(a, b, c) __builtin_amdgcn_mfma_f32_16x16x32_bf16(a, b, c, 0, 0, 0)

__device__ __forceinline__ short f2bf(float f) {
  union { float f; unsigned int i; } v; v.f = f;
  unsigned int r = v.i + 0x7FFFu + ((v.i >> 16) & 1u);  // RNE
  return (short)(r >> 16);
}

__device__ __forceinline__ void gload_lds16(const void* g, void* l) {
  __builtin_amdgcn_global_load_lds(
      (const __attribute__((address_space(1))) void*)g,
      (__attribute__((address_space(3))) void*)l, 16, 0, 0);
}

// ---------------------------------------------------------------------------
// Fused f32 -> bf16 conversion for all 7 tensors (one launch).
// ---------------------------------------------------------------------------
__global__ __launch_bounds__(256) void cvt_all(
    const float* __restrict__ q, const float* __restrict__ k, const float* __restrict__ v,
    const float* __restrict__ wq, const float* __restrict__ wk,
    const float* __restrict__ wv, const float* __restrict__ wo,
    short* __restrict__ qb, short* __restrict__ kb, short* __restrict__ vb,
    short* __restrict__ wqb, short* __restrict__ wkb,
    short* __restrict__ wvb, short* __restrict__ wob) {
  const int total = 16 * 1048576 / 4;  // vec4 count
  int stride = gridDim.x * blockDim.x;
  for (int i = blockIdx.x * blockDim.x + threadIdx.x; i < total; i += stride) {
    int e = i * 4;
    int chunk = e >> 20;
    const float* s;
    short* d;
    int off;
    if (chunk < 12) {
      if (chunk < 4)      { s = q; d = qb; }
      else if (chunk < 8) { s = k; d = kb; }
      else                { s = v; d = vb; }
      off = e & (4 * 1048576 - 1);
    } else {
      int w = chunk - 12;
      if (w == 0)      { s = wq; d = wqb; }
      else if (w == 1) { s = wk; d = wkb; }
      else if (w == 2) { s = wv; d = wvb; }
      else             { s = wo; d = wob; }
      off = e & (1048576 - 1);
    }
    float4 x = *(const float4*)(s + off);
    short4 o;
    o.x = f2bf(x.x); o.y = f2bf(x.y); o.z = f2bf(x.z); o.w = f2bf(x.w);
    *(short4*)(d + off) = o;
  }
}

// ---------------------------------------------------------------------------
// Fused Q/K/V projection: 256x64 tile, 4 waves stacked, BK=64 (round 3).
// ---------------------------------------------------------------------------
__global__ __launch_bounds__(256) void proj_qkv(
    const short* __restrict__ qA, const short* __restrict__ kA, const short* __restrict__ vA,
    const short* __restrict__ Wqb, const short* __restrict__ Wkb, const short* __restrict__ Wvb,
    const float* __restrict__ bq, const float* __restrict__ bk, const float* __restrict__ bv,
    short* __restrict__ Qh, short* __restrict__ Kh, short* __restrict__ Vth) {
  __shared__ short SMEM[256 * 64 + 64 * 64];  // As(32K) + Bs(8K); reused as Vt
  short* As = SMEM;
  short* Bs = SMEM + 256 * 64;

  const int m0 = blockIdx.x * 256;
  const int n0 = blockIdx.y * 64;
  const int z = blockIdx.z;

  const short *A, *W;
  const float* bias;
  if (z == 0)      { A = qA; W = Wqb; bias = bq; }
  else if (z == 1) { A = kA; W = Wkb; bias = bk; }
  else             { A = vA; W = Wvb; bias = bv; }

  const int tid = threadIdx.x;
  const int wid = tid >> 6, lane = tid & 63;
  const int fr = lane & 15, fq = lane >> 4;

  f32x4 acc[4][4] = {};

  for (int kt = 0; kt < 16; ++kt) {
#pragma unroll
    for (int c = 0; c < 8; ++c) {
      int pbase = c * 4096 + wid * 1024;
      int pb = pbase + lane * 16;
      int lb = pb ^ (((pb >> 7) & 7) << 4);
      int grow = lb >> 7, gcol = (lb & 127) >> 1;
      gload_lds16(A + (size_t)(m0 + grow) * 1024 + kt * 64 + gcol, (char*)As + pbase);
    }
#pragma unroll
    for (int c = 0; c < 2; ++c) {
      int pbase = c * 4096 + wid * 1024;
      int pb = pbase + lane * 16;
      int lb = pb ^ (((pb >> 7) & 7) << 4);
      int grow = lb >> 7, gcol = (lb & 127) >> 1;
      gload_lds16(W + (size_t)(n0 + grow) * 1024 + kt * 64 + gcol, (char*)Bs + pbase);
    }
    __syncthreads();
#pragma unroll
    for (int kk = 0; kk < 2; ++kk) {
      bf16x8 af[4], bg[4];
      int cb = (fq * 8 + kk * 32) * 2;
#pragma unroll
      for (int m = 0; m < 4; ++m) {
        int r = wid * 64 + m * 16 + fr;
        af[m] = *(const bf16x8*)((const char*)As + (((r << 7) + cb) ^ ((r & 7) << 4)));
      }
#pragma unroll
      for (int n = 0; n < 4; ++n) {
        int r = n * 16 + fr;
        bg[n] = *(const bf16x8*)((const char*)Bs + (((r << 7) + cb) ^ ((r & 7) << 4)));
      }
#pragma unroll
      for (int m = 0; m < 4; ++m)
#pragma unroll
        for (int n = 0; n < 4; ++n)
          acc[m][n] = MFMA16(af[m], bg[n], acc[m][n]);
    }
    __syncthreads();
  }

  if (z < 2) {
    short* dst = (z == 0) ? Qh : Kh;
#pragma unroll
    for (int m = 0; m < 4; ++m)
#pragma unroll
      for (int n = 0; n < 4; ++n) {
        int col = n0 + n * 16 + fr;
        float bval = bias[col];
        int row0 = m0 + wid * 64 + m * 16 + fq * 4;
        int hh = col >> 6, dh = col & 63;
#pragma unroll
        for (int j = 0; j < 4; ++j) {
          int row = row0 + j;
          int bb = row >> 10, t = row & 1023;
          dst[(((size_t)(bb * 16 + hh)) * 1024 + t) * 64 + dh] = f2bf(acc[m][n][j] + bval);
        }
      }
  } else {
    short* Vt = SMEM;  // [64][264] shorts
#pragma unroll
    for (int m = 0; m < 4; ++m)
#pragma unroll
      for (int n = 0; n < 4; ++n) {
        int coll = n * 16 + fr;
        float bval = bias[n0 + coll];
        int rowl0 = wid * 64 + m * 16 + fq * 4;
#pragma unroll
        for (int j = 0; j < 4; ++j)
          Vt[coll * 264 + rowl0 + j] = f2bf(acc[m][n][j] + bval);
      }
    __syncthreads();
    const int bb = m0 >> 10, t0 = m0 & 1023;
#pragma unroll
    for (int it = 0; it < 8; ++it) {
      int qq = tid + it * 256;
      int rowl = qq >> 5, seg = qq & 31;
      bf16x8 vv = *(const bf16x8*)&Vt[rowl * 264 + seg * 8];
      int cg = n0 + rowl, hh = cg >> 6, dh = cg & 63;
      *(bf16x8*)&Vth[(((size_t)(bb * 16 + hh)) * 64 + dh) * 1024 + t0 + seg * 8] = vv;
    }
  }
}

// ---------------------------------------------------------------------------
// Output projection: 512 thr / 8 waves, 256x64 tile (round 3).
// ---------------------------------------------------------------------------
__global__ __launch_bounds__(512) void gemm_out(const short* __restrict__ A,
                                                const short* __restrict__ W,
                                                const float* __restrict__ bias,
                                                float* __restrict__ C) {
  __shared__ short As[256 * 64];
  __shared__ short Bs[64 * 64];
  const int m0 = blockIdx.x * 256;
  const int n0 = blockIdx.y * 64;

  const int tid = threadIdx.x;
  const int wid = tid >> 6, lane = tid & 63;
  const int fr = lane & 15, fq = lane >> 4;

  f32x4 acc[2][4] = {};

  for (int kt = 0; kt < 16; ++kt) {
#pragma unroll
    for (int c = 0; c < 4; ++c) {
      int pbase = c * 8192 + wid * 1024;
      int pb = pbase + lane * 16;
      int lb = pb ^ (((pb >> 7) & 7) << 4);
      int grow = lb >> 7, gcol = (lb & 127) >> 1;
      gload_lds16(A + (size_t)(m0 + grow) * 1024 + kt * 64 + gcol, (char*)As + pbase);
    }
    {
      int pbase = wid * 1024;
      int pb = pbase + lane * 16;
      int lb = pb ^ (((pb >> 7) & 7) << 4);
      int grow = lb >> 7, gcol = (lb & 127) >> 1;
      gload_lds16(W + (size_t)(n0 + grow) * 1024 + kt * 64 + gcol, (char*)Bs + pbase);
    }
    __syncthreads();
#pragma unroll
    for (int kk = 0; kk < 2; ++kk) {
      bf16x8 af[2], bg[4];
      int cb = (fq * 8 + kk * 32) * 2;
#pragma unroll
      for (int m = 0; m < 2; ++m) {
        int r = wid * 32 + m * 16 + fr;
        af[m] = *(const bf16x8*)((const char*)As + (((r << 7) + cb) ^ ((r & 7) << 4)));
      }
#pragma unroll
      for (int n = 0; n < 4; ++n) {
        int r = n * 16 + fr;
        bg[n] = *(const bf16x8*)((const char*)Bs + (((r << 7) + cb) ^ ((r & 7) << 4)));
      }
#pragma unroll
      for (int m = 0; m < 2; ++m)
#pragma unroll
        for (int n = 0; n < 4; ++n)
          acc[m][n] = MFMA16(af[m], bg[n], acc[m][n]);
    }
    __syncthreads();
  }

#pragma unroll
  for (int m = 0; m < 2; ++m)
#pragma unroll
    for (int n = 0; n < 4; ++n) {
      int col = n0 + n * 16 + fr;
      float bval = bias[col];
      int row0 = m0 + wid * 32 + m * 16 + fq * 4;
#pragma unroll
      for (int j = 0; j < 4; ++j)
        C[(size_t)(row0 + j) * 1024 + col] = acc[m][n][j] + bval;
    }
}

// ---------------------------------------------------------------------------
// Flash attention per head: grid (16 q-tiles, 64 heads), 256 thr (4 waves).
// BARRIER-FREE: K/V fragments read directly from global (L2-resident: 128KB
// per head). LDS = per-wave Ps only (stride 84 shorts -> conflict-free).
// Bias/mask prefetched one KV-tile ahead in registers. Causal cndmask only
// on the diagonal tile. Online softmax fp32.
// ---------------------------------------------------------------------------
__global__ __launch_bounds__(256) void attn_kernel(
    const short* __restrict__ Qh, const short* __restrict__ Kh,
    const short* __restrict__ Vth, const float* __restrict__ Wb,
    const float* __restrict__ mask, short* __restrict__ Aout) {
  __shared__ short Ps[4][16 * 84];  // per-wave P tile, 168B rows

  const int tid = threadIdx.x;
  const int wid = tid >> 6, lane = tid & 63;
  const int fr = lane & 15, fq = lane >> 4;
  const int h = blockIdx.y, b = h >> 4;
  const int qi = (int)gridDim.x - 1 - (int)blockIdx.x;  // heavy tiles first
  const int q0 = qi * 64;
  const int qrow0 = q0 + wid * 16;

  const short* qbase = Qh + ((size_t)h * 1024 + qrow0 + fr) * 64 + fq * 8;
  bf16x8 qf0 = *(const bf16x8*)qbase;
  bf16x8 qf1 = *(const bf16x8*)(qbase + 32);

  const short* Kbase = Kh + (size_t)h * 1024 * 64;
  const short* Vbase = Vth + (size_t)h * 64 * 1024;
  const float* wbase = Wb + (size_t)h * 1024 * 1024;
  const float* mbase = mask + b * 1024;

  // raw prefetch (no arithmetic at load site -> no early vmcnt stall)
  auto load_bias = [&](float (&bv)[4][4], float (&mk)[4], int k0) {
#pragma unroll
    for (int nt = 0; nt < 4; ++nt) {
      mk[nt] = mbase[k0 + nt * 16 + fr];
#pragma unroll
      for (int j = 0; j < 4; ++j)
        bv[nt][j] = wbase[(size_t)(qrow0 + fq * 4 + j) * 1024 + (k0 + nt * 16 + fr)];
    }
  };

  f32x4 o_acc[4] = {};
  float m_run[4], l_run[4];
#pragma unroll
  for (int j = 0; j < 4; ++j) { m_run[j] = -3.0e38f; l_run[j] = 0.f; }

  float bias_cur[4][4], bias_nxt[4][4], mk_cur[4], mk_nxt[4];
  load_bias(bias_cur, mk_cur, 0);

  for (int kt = 0; kt <= qi; ++kt) {
    const int k0 = kt * 64;
    if (kt < qi) load_bias(bias_nxt, mk_nxt, k0 + 64);  // reg prefetch (T14)
    const bool diag = (kt == qi);

    // S = Q K^T  (K frags straight from L2)
    f32x4 s_acc[4] = {};
#pragma unroll
    for (int kk = 0; kk < 2; ++kk)
#pragma unroll
      for (int nt = 0; nt < 4; ++nt) {
        bf16x8 kf = *(const bf16x8*)(Kbase + (size_t)(k0 + nt * 16 + fr) * 64 + fq * 8 + kk * 32);
        s_acc[nt] = MFMA16(kk == 0 ? qf0 : qf1, kf, s_acc[nt]);
      }

    // mask penalty per key column (off the per-element path)
    float pen[4];
#pragma unroll
    for (int nt = 0; nt < 4; ++nt) pen[nt] = (1.0f - mk_cur[nt]) * 3.125e8f;

    // scale + bias + masks + online softmax (fp32)
    float p[4][4];
#pragma unroll
    for (int j = 0; j < 4; ++j) {
      const int rq = qrow0 + fq * 4 + j;
      float mx = -3.0e38f;
#pragma unroll
      for (int nt = 0; nt < 4; ++nt) {
        float s = (s_acc[nt][j] + bias_cur[nt][j]) * 0.03125f - pen[nt];
        if (diag) {
          int ck = k0 + nt * 16 + fr;
          if (ck > rq) s = -3.0e38f;  // causal (diagonal tile only)
        }
        p[nt][j] = s;
        mx = fmaxf(mx, s);
      }
#pragma unroll
      for (int d = 1; d < 16; d <<= 1) mx = fmaxf(mx, __shfl_xor(mx, d, 16));
      float mnew = fmaxf(m_run[j], mx);
      float corr = __expf(m_run[j] - mnew);
      m_run[j] = mnew;
      float rsum = 0.f;
#pragma unroll
      for (int nt = 0; nt < 4; ++nt) {
        float e = __expf(p[nt][j] - mnew);
        p[nt][j] = e;
        rsum += e;
      }
#pragma unroll
      for (int d = 1; d < 16; d <<= 1) rsum += __shfl_xor(rsum, d, 16);
      l_run[j] = l_run[j] * corr + rsum;
#pragma unroll
      for (int nt = 0; nt < 4; ++nt) o_acc[nt][j] *= corr;
    }

    // P (C-layout) -> per-wave LDS -> A-layout frags  (intra-wave, no barrier)
#pragma unroll
    for (int nt = 0; nt < 4; ++nt)
#pragma unroll
      for (int j = 0; j < 4; ++j)
        Ps[wid][(fq * 4 + j) * 84 + nt * 16 + fr] = f2bf(p[nt][j]);
    asm volatile("s_waitcnt lgkmcnt(0)" ::: "memory");
    bf16x8 pf0 = *(const bf16x8*)&Ps[wid][fr * 84 + fq * 8];
    bf16x8 pf1 = *(const bf16x8*)&Ps[wid][fr * 84 + fq * 8 + 32];

    // O += P V  (V^T frags straight from L2)
#pragma unroll
    for (int kk = 0; kk < 2; ++kk)
#pragma unroll
      for (int nt = 0; nt < 4; ++nt) {
        bf16x8 vf = *(const bf16x8*)(Vbase + (size_t)(nt * 16 + fr) * 1024 + k0 + fq * 8 + kk * 32);
        o_acc[nt] = MFMA16(kk == 0 ? pf0 : pf1, vf, o_acc[nt]);
      }

    if (kt < qi) {
#pragma unroll
      for (int nt = 0; nt < 4; ++nt) {
        mk_cur[nt] = mk_nxt[nt];
#pragma unroll
        for (int j = 0; j < 4; ++j) bias_cur[nt][j] = bias_nxt[nt][j];
      }
    }
  }

  // normalize + write merged-head bf16 [4096][1024]
#pragma unroll
  for (int nt = 0; nt < 4; ++nt)
#pragma unroll
    for (int j = 0; j < 4; ++j) {
      int row = b * 1024 + q0 + wid * 16 + fq * 4 + j;
      int col = (h & 15) * 64 + nt * 16 + fr;
      Aout[(size_t)row * 1024 + col] = f2bf(o_acc[nt][j] / l_run[j]);
    }
}

// ---------------------------------------------------------------------------
extern "C" void kernel_launch(void* const* d_in, const int* in_sizes, int n_in,
                              void* d_out, int out_size, void* d_ws, size_t ws_size,
                              hipStream_t stream) {
  const float* query = (const float*)d_in[0];
  const float* key   = (const float*)d_in[1];
  const float* value = (const float*)d_in[2];
  const float* mask  = (const float*)d_in[3];
  const float* wts   = (const float*)d_in[4];
  const float* Wq    = (const float*)d_in[5];
  const float* bq    = (const float*)d_in[6];
  const float* Wk    = (const float*)d_in[7];
  const float* bk    = (const float*)d_in[8];
  const float* Wv    = (const float*)d_in[9];
  const float* bv    = (const float*)d_in[10];
  const float* Wo    = (const float*)d_in[11];
  const float* bo    = (const float*)d_in[12];

  char* ws = (char*)d_ws;
  const size_t MB = 1u << 20;
  short* qbf = (short*)(ws + 0);        // 8 MB  (reused as attn out)
  short* kbf = (short*)(ws + 8 * MB);   // 8 MB
  short* vbf = (short*)(ws + 16 * MB);  // 8 MB
  short* Wqb = (short*)(ws + 24 * MB);  // 2 MB
  short* Wkb = (short*)(ws + 26 * MB);
  short* Wvb = (short*)(ws + 28 * MB);
  short* Wob = (short*)(ws + 30 * MB);
  short* Qh  = (short*)(ws + 32 * MB);  // 8 MB [B,N,T,DH]
  short* Kh  = (short*)(ws + 40 * MB);  // 8 MB [B,N,T,DH]
  short* Vth = (short*)(ws + 48 * MB);  // 8 MB [B,N,DH,T]
  short* attnb = qbf;                   // alias: qbf dead after proj_qkv

  cvt_all<<<dim3(2048), dim3(256), 0, stream>>>(query, key, value, Wq, Wk, Wv, Wo,
                                                qbf, kbf, vbf, Wqb, Wkb, Wvb, Wob);
  proj_qkv<<<dim3(16, 16, 3), dim3(256), 0, stream>>>(qbf, kbf, vbf, Wqb, Wkb, Wvb,
                                                      bq, bk, bv, Qh, Kh, Vth);
  attn_kernel<<<dim3(16, 64), dim3(256), 0, stream>>>(Qh, Kh, Vth, wts, mask, attnb);
  gemm_out<<<dim3(16, 16), dim3(512), 0, stream>>>(attnb, Wob, bo, (float*)d_out);
}

// Round 6
// 170.648 us; speedup vs baseline: 7.3330x; 1.2917x over previous
//
#include <hip/hip_runtime.h>
#include <cstddef>

// ---------------------------------------------------------------------------
// MultiHead attention, B=4 T=1024 D=1024 N=16 DH=64, SCALE=32, causal + bias.
// Round 6: attn restructured — swapped QK^T (S^T = K·Q^T) makes each lane own
// one q-row: softmax = local reduce + 2 shuffles (was 32 shuffles/tile).
// Bias tile async-staged to LDS (double-buffered, swizzled) instead of 16
// scalar register loads. K/V staged dbuf as in round 3.
// ---------------------------------------------------------------------------

typedef __attribute__((ext_vector_type(8))) short bf16x8;
typedef __attribute__((ext_vector_type(4))) float f32x4;

#define MFMA16(a, b, c) __builtin_amdgcn_mfma_f32_16x16x32_bf16(a, b, c, 0, 0, 0)

__device__ __forceinline__ short f2bf(float f) {
  union { float f; unsigned int i; } v; v.f = f;
  unsigned int r = v.i + 0x7FFFu + ((v.i >> 16) & 1u);  // RNE
  return (short)(r >> 16);
}

__device__ __forceinline__ void gload_lds16(const void* g, void* l) {
  __builtin_amdgcn_global_load_lds(
      (const __attribute__((address_space(1))) void*)g,
      (__attribute__((address_space(3))) void*)l, 16, 0, 0);
}

// ---------------------------------------------------------------------------
// Fused f32 -> bf16 conversion for all 7 tensors (one launch).
// ---------------------------------------------------------------------------
__global__ __launch_bounds__(256) void cvt_all(
    const float* __restrict__ q, const float* __restrict__ k, const float* __restrict__ v,
    const float* __restrict__ wq, const float* __restrict__ wk,
    const float* __restrict__ wv, const float* __restrict__ wo,
    short* __restrict__ qb, short* __restrict__ kb, short* __restrict__ vb,
    short* __restrict__ wqb, short* __restrict__ wkb,
    short* __restrict__ wvb, short* __restrict__ wob) {
  const int total = 16 * 1048576 / 4;  // vec4 count
  int stride = gridDim.x * blockDim.x;
  for (int i = blockIdx.x * blockDim.x + threadIdx.x; i < total; i += stride) {
    int e = i * 4;
    int chunk = e >> 20;
    const float* s;
    short* d;
    int off;
    if (chunk < 12) {
      if (chunk < 4)      { s = q; d = qb; }
      else if (chunk < 8) { s = k; d = kb; }
      else                { s = v; d = vb; }
      off = e & (4 * 1048576 - 1);
    } else {
      int w = chunk - 12;
      if (w == 0)      { s = wq; d = wqb; }
      else if (w == 1) { s = wk; d = wkb; }
      else if (w == 2) { s = wv; d = wvb; }
      else             { s = wo; d = wob; }
      off = e & (1048576 - 1);
    }
    float4 x = *(const float4*)(s + off);
    short4 o;
    o.x = f2bf(x.x); o.y = f2bf(x.y); o.z = f2bf(x.z); o.w = f2bf(x.w);
    *(short4*)(d + off) = o;
  }
}

// ---------------------------------------------------------------------------
// Fused Q/K/V projection: 256x64 tile, 4 waves stacked, BK=64 (round 3).
// ---------------------------------------------------------------------------
__global__ __launch_bounds__(256) void proj_qkv(
    const short* __restrict__ qA, const short* __restrict__ kA, const short* __restrict__ vA,
    const short* __restrict__ Wqb, const short* __restrict__ Wkb, const short* __restrict__ Wvb,
    const float* __restrict__ bq, const float* __restrict__ bk, const float* __restrict__ bv,
    short* __restrict__ Qh, short* __restrict__ Kh, short* __restrict__ Vth) {
  __shared__ short SMEM[256 * 64 + 64 * 64];  // As(32K) + Bs(8K); reused as Vt
  short* As = SMEM;
  short* Bs = SMEM + 256 * 64;

  const int m0 = blockIdx.x * 256;
  const int n0 = blockIdx.y * 64;
  const int z = blockIdx.z;

  const short *A, *W;
  const float* bias;
  if (z == 0)      { A = qA; W = Wqb; bias = bq; }
  else if (z == 1) { A = kA; W = Wkb; bias = bk; }
  else             { A = vA; W = Wvb; bias = bv; }

  const int tid = threadIdx.x;
  const int wid = tid >> 6, lane = tid & 63;
  const int fr = lane & 15, fq = lane >> 4;

  f32x4 acc[4][4] = {};

  for (int kt = 0; kt < 16; ++kt) {
#pragma unroll
    for (int c = 0; c < 8; ++c) {
      int pbase = c * 4096 + wid * 1024;
      int pb = pbase + lane * 16;
      int lb = pb ^ (((pb >> 7) & 7) << 4);
      int grow = lb >> 7, gcol = (lb & 127) >> 1;
      gload_lds16(A + (size_t)(m0 + grow) * 1024 + kt * 64 + gcol, (char*)As + pbase);
    }
#pragma unroll
    for (int c = 0; c < 2; ++c) {
      int pbase = c * 4096 + wid * 1024;
      int pb = pbase + lane * 16;
      int lb = pb ^ (((pb >> 7) & 7) << 4);
      int grow = lb >> 7, gcol = (lb & 127) >> 1;
      gload_lds16(W + (size_t)(n0 + grow) * 1024 + kt * 64 + gcol, (char*)Bs + pbase);
    }
    __syncthreads();
#pragma unroll
    for (int kk = 0; kk < 2; ++kk) {
      bf16x8 af[4], bg[4];
      int cb = (fq * 8 + kk * 32) * 2;
#pragma unroll
      for (int m = 0; m < 4; ++m) {
        int r = wid * 64 + m * 16 + fr;
        af[m] = *(const bf16x8*)((const char*)As + (((r << 7) + cb) ^ ((r & 7) << 4)));
      }
#pragma unroll
      for (int n = 0; n < 4; ++n) {
        int r = n * 16 + fr;
        bg[n] = *(const bf16x8*)((const char*)Bs + (((r << 7) + cb) ^ ((r & 7) << 4)));
      }
#pragma unroll
      for (int m = 0; m < 4; ++m)
#pragma unroll
        for (int n = 0; n < 4; ++n)
          acc[m][n] = MFMA16(af[m], bg[n], acc[m][n]);
    }
    __syncthreads();
  }

  if (z < 2) {
    short* dst = (z == 0) ? Qh : Kh;
#pragma unroll
    for (int m = 0; m < 4; ++m)
#pragma unroll
      for (int n = 0; n < 4; ++n) {
        int col = n0 + n * 16 + fr;
        float bval = bias[col];
        int row0 = m0 + wid * 64 + m * 16 + fq * 4;
        int hh = col >> 6, dh = col & 63;
#pragma unroll
        for (int j = 0; j < 4; ++j) {
          int row = row0 + j;
          int bb = row >> 10, t = row & 1023;
          dst[(((size_t)(bb * 16 + hh)) * 1024 + t) * 64 + dh] = f2bf(acc[m][n][j] + bval);
        }
      }
  } else {
    short* Vt = SMEM;  // [64][264] shorts
#pragma unroll
    for (int m = 0; m < 4; ++m)
#pragma unroll
      for (int n = 0; n < 4; ++n) {
        int coll = n * 16 + fr;
        float bval = bias[n0 + coll];
        int rowl0 = wid * 64 + m * 16 + fq * 4;
#pragma unroll
        for (int j = 0; j < 4; ++j)
          Vt[coll * 264 + rowl0 + j] = f2bf(acc[m][n][j] + bval);
      }
    __syncthreads();
    const int bb = m0 >> 10, t0 = m0 & 1023;
#pragma unroll
    for (int it = 0; it < 8; ++it) {
      int qq = tid + it * 256;
      int rowl = qq >> 5, seg = qq & 31;
      bf16x8 vv = *(const bf16x8*)&Vt[rowl * 264 + seg * 8];
      int cg = n0 + rowl, hh = cg >> 6, dh = cg & 63;
      *(bf16x8*)&Vth[(((size_t)(bb * 16 + hh)) * 64 + dh) * 1024 + t0 + seg * 8] = vv;
    }
  }
}

// ---------------------------------------------------------------------------
// Output projection: 512 thr / 8 waves, 256x64 tile (round 3).
// ---------------------------------------------------------------------------
__global__ __launch_bounds__(512) void gemm_out(const short* __restrict__ A,
                                                const short* __restrict__ W,
                                                const float* __restrict__ bias,
                                                float* __restrict__ C) {
  __shared__ short As[256 * 64];
  __shared__ short Bs[64 * 64];
  const int m0 = blockIdx.x * 256;
  const int n0 = blockIdx.y * 64;

  const int tid = threadIdx.x;
  const int wid = tid >> 6, lane = tid & 63;
  const int fr = lane & 15, fq = lane >> 4;

  f32x4 acc[2][4] = {};

  for (int kt = 0; kt < 16; ++kt) {
#pragma unroll
    for (int c = 0; c < 4; ++c) {
      int pbase = c * 8192 + wid * 1024;
      int pb = pbase + lane * 16;
      int lb = pb ^ (((pb >> 7) & 7) << 4);
      int grow = lb >> 7, gcol = (lb & 127) >> 1;
      gload_lds16(A + (size_t)(m0 + grow) * 1024 + kt * 64 + gcol, (char*)As + pbase);
    }
    {
      int pbase = wid * 1024;
      int pb = pbase + lane * 16;
      int lb = pb ^ (((pb >> 7) & 7) << 4);
      int grow = lb >> 7, gcol = (lb & 127) >> 1;
      gload_lds16(W + (size_t)(n0 + grow) * 1024 + kt * 64 + gcol, (char*)Bs + pbase);
    }
    __syncthreads();
#pragma unroll
    for (int kk = 0; kk < 2; ++kk) {
      bf16x8 af[2], bg[4];
      int cb = (fq * 8 + kk * 32) * 2;
#pragma unroll
      for (int m = 0; m < 2; ++m) {
        int r = wid * 32 + m * 16 + fr;
        af[m] = *(const bf16x8*)((const char*)As + (((r << 7) + cb) ^ ((r & 7) << 4)));
      }
#pragma unroll
      for (int n = 0; n < 4; ++n) {
        int r = n * 16 + fr;
        bg[n] = *(const bf16x8*)((const char*)Bs + (((r << 7) + cb) ^ ((r & 7) << 4)));
      }
#pragma unroll
      for (int m = 0; m < 2; ++m)
#pragma unroll
        for (int n = 0; n < 4; ++n)
          acc[m][n] = MFMA16(af[m], bg[n], acc[m][n]);
    }
    __syncthreads();
  }

#pragma unroll
  for (int m = 0; m < 2; ++m)
#pragma unroll
    for (int n = 0; n < 4; ++n) {
      int col = n0 + n * 16 + fr;
      float bval = bias[col];
      int row0 = m0 + wid * 32 + m * 16 + fq * 4;
#pragma unroll
      for (int j = 0; j < 4; ++j)
        C[(size_t)(row0 + j) * 1024 + col] = acc[m][n][j] + bval;
    }
}

// ---------------------------------------------------------------------------
// Flash attention: grid (16 q-tiles, 64 heads), 256 thr (4 waves).
// SWAPPED QK^T: s_acc = mfma(K_frag, Q_frag) -> S^T[k][q], q = lane&15.
// Each lane owns ONE q-row: softmax = 15 local fmax + 2 shuffles.
// K/V + bias tiles double-buffered in LDS via async global_load_lds,
// drained by the single end-of-tile barrier. PV: o = mfma(V^T_frag, P_frag).
// ---------------------------------------------------------------------------
__global__ __launch_bounds__(256) void attn_kernel(
    const short* __restrict__ Qh, const short* __restrict__ Kh,
    const short* __restrict__ Vth, const float* __restrict__ Wb,
    const float* __restrict__ mask, short* __restrict__ Aout) {
  __shared__ short Ks[2][64 * 64];    // 8 KB x2, row&7 swizzle (128B rows)
  __shared__ short Vs[2][64 * 64];    // 8 KB x2
  __shared__ float Bi[2][4096];       // 16 KB x2 bias tile, row&7 swizzle (256B rows)
  __shared__ short Ps[4][16 * 84];    // per-wave P, 168B rows

  const int tid = threadIdx.x;
  const int wid = tid >> 6, lane = tid & 63;
  const int fr = lane & 15, fq = lane >> 4;
  const int h = blockIdx.y, b = h >> 4;
  const int qi = (int)gridDim.x - 1 - (int)blockIdx.x;  // heavy tiles first
  const int q0 = qi * 64;
  const int qrow0 = q0 + wid * 16;

  // Q fragment (B-operand): Q[qrow0+fr][fq*8 + {0..7}] (+32 for kk=1)
  const short* qbase = Qh + ((size_t)h * 1024 + qrow0 + fr) * 64 + fq * 8;
  bf16x8 qf0 = *(const bf16x8*)qbase;
  bf16x8 qf1 = *(const bf16x8*)(qbase + 32);

  const short* Kbase = Kh + (size_t)h * 1024 * 64;
  const short* Vbase = Vth + (size_t)h * 64 * 1024;
  const float* wbase = Wb + (size_t)h * 1024 * 1024;
  const float4* mask4 = (const float4*)(mask + b * 1024);

  auto stage = [&](int buf, int k0) {
    // K tile [t 0..63][dh 0..63] bf16, V^T tile [dh][t]; 128B rows, swz row&7
#pragma unroll
    for (int c = 0; c < 2; ++c) {
      int pbase = c * 4096 + wid * 1024;
      int pb = pbase + lane * 16;
      int lb = pb ^ (((pb >> 7) & 7) << 4);
      int grow = lb >> 7, gcol = (lb & 127) >> 1;
      gload_lds16(Kbase + (size_t)(k0 + grow) * 64 + gcol, (char*)Ks[buf] + pbase);
      gload_lds16(Vbase + (size_t)grow * 1024 + k0 + gcol, (char*)Vs[buf] + pbase);
    }
    // bias tile [q-row 0..63][k 0..63] f32, 256B rows, swz row&7 on bits 4-6
#pragma unroll
    for (int c = 0; c < 4; ++c) {
      int pbase = c * 4096 + wid * 1024;
      int pb = pbase + lane * 16;
      int lb = pb ^ (((pb >> 8) & 7) << 4);
      int grow = lb >> 8, gcolf = (lb & 255) >> 2;
      gload_lds16(wbase + (size_t)(q0 + grow) * 1024 + k0 + gcolf, (char*)Bi[buf] + pbase);
    }
  };

  f32x4 o_acc[4] = {};
  float m_run = -3.0e38f, l_run = 0.f;

  stage(0, 0);
  __syncthreads();
  int cur = 0;

  for (int kt = 0; kt <= qi; ++kt) {
    const int k0 = kt * 64;
    if (kt < qi) stage(cur ^ 1, k0 + 64);  // async prefetch, drained at barrier
    const bool diag = (kt == qi);

    // mask values per k = nt*16 + fq*4 + {0..3}
    float4 mkv[4];
#pragma unroll
    for (int nt = 0; nt < 4; ++nt) mkv[nt] = mask4[(k0 >> 2) + nt * 4 + fq];

    // S^T = K·Q^T : s_acc[nt][j] = S[k = k0+nt*16+fq*4+j][q = qrow0+fr]
    f32x4 s_acc[4] = {};
#pragma unroll
    for (int kk = 0; kk < 2; ++kk)
#pragma unroll
      for (int nt = 0; nt < 4; ++nt) {
        int r = nt * 16 + fr;
        int cb = fq * 16 + kk * 64;
        bf16x8 kf = *(const bf16x8*)((const char*)Ks[cur] + (((r << 7) + cb) ^ ((r & 7) << 4)));
        s_acc[nt] = MFMA16(kf, kk == 0 ? qf0 : qf1, s_acc[nt]);
      }

    // bias[q = wid*16+fr][k = nt*16+fq*4+{0..3}] from swizzled LDS
    float4 bv[4];
#pragma unroll
    for (int nt = 0; nt < 4; ++nt) {
      int lbyte = (wid * 16 + fr) * 256 + nt * 64 + fq * 16;
      bv[nt] = *(const float4*)((const char*)Bi[cur] + (lbyte ^ ((fr & 7) << 4)));
    }

    // softmax for this lane's q-row (all 16 k-values local)
    float p[4][4];
    float mx = -3.0e38f;
#pragma unroll
    for (int nt = 0; nt < 4; ++nt)
#pragma unroll
      for (int j = 0; j < 4; ++j) {
        float mkj = (j == 0) ? mkv[nt].x : (j == 1) ? mkv[nt].y : (j == 2) ? mkv[nt].z : mkv[nt].w;
        float s = (s_acc[nt][j] + bv[nt][j]) * 0.03125f - (1.0f - mkj) * 3.125e8f;
        if (diag && (nt * 16 + fq * 4 + j) > (wid * 16 + fr)) s = -3.0e38f;
        p[nt][j] = s;
        mx = fmaxf(mx, s);
      }
    mx = fmaxf(mx, __shfl_xor(mx, 16));
    mx = fmaxf(mx, __shfl_xor(mx, 32));
    float mnew = fmaxf(m_run, mx);
    float corr = __expf(m_run - mnew);
    m_run = mnew;
    float rsum = 0.f;
#pragma unroll
    for (int nt = 0; nt < 4; ++nt)
#pragma unroll
      for (int j = 0; j < 4; ++j) {
        float e = __expf(p[nt][j] - mnew);
        p[nt][j] = e;
        rsum += e;
      }
    rsum += __shfl_xor(rsum, 16);
    rsum += __shfl_xor(rsum, 32);
    l_run = l_run * corr + rsum;
#pragma unroll
    for (int nt = 0; nt < 4; ++nt) o_acc[nt] *= corr;

    // P[q = fr][k = nt*16+fq*4+{0..3}] -> per-wave LDS (packed u32 writes)
#pragma unroll
    for (int nt = 0; nt < 4; ++nt) {
      unsigned int lo = (unsigned short)f2bf(p[nt][0]) |
                        ((unsigned int)(unsigned short)f2bf(p[nt][1]) << 16);
      unsigned int hi = (unsigned short)f2bf(p[nt][2]) |
                        ((unsigned int)(unsigned short)f2bf(p[nt][3]) << 16);
      *(unsigned int*)&Ps[wid][fr * 84 + nt * 16 + fq * 4] = lo;
      *(unsigned int*)&Ps[wid][fr * 84 + nt * 16 + fq * 4 + 2] = hi;
    }
    asm volatile("s_waitcnt lgkmcnt(0)" ::: "memory");
    bf16x8 pf0 = *(const bf16x8*)&Ps[wid][fr * 84 + fq * 8];        // B[col=q][k]
    bf16x8 pf1 = *(const bf16x8*)&Ps[wid][fr * 84 + fq * 8 + 32];

    // O^T = V^T · P : o_acc[nt2][j] = O[q = qrow0+fr][d = nt2*16+fq*4+j]
#pragma unroll
    for (int kk = 0; kk < 2; ++kk)
#pragma unroll
      for (int nt = 0; nt < 4; ++nt) {
        int r = nt * 16 + fr;
        int cb = fq * 16 + kk * 64;
        bf16x8 vf = *(const bf16x8*)((const char*)Vs[cur] + (((r << 7) + cb) ^ ((r & 7) << 4)));
        o_acc[nt] = MFMA16(vf, kk == 0 ? pf0 : pf1, o_acc[nt]);
      }

    __syncthreads();  // all waves done with [cur]; prefetch into [cur^1] drained
    cur ^= 1;
  }

  // normalize + write merged-head bf16 [4096][1024]; short4 per nt2
  float rl = 1.0f / l_run;
  size_t row = (size_t)(b * 1024 + q0 + wid * 16 + fr);
#pragma unroll
  for (int nt = 0; nt < 4; ++nt) {
    short4 sv;
    sv.x = f2bf(o_acc[nt][0] * rl);
    sv.y = f2bf(o_acc[nt][1] * rl);
    sv.z = f2bf(o_acc[nt][2] * rl);
    sv.w = f2bf(o_acc[nt][3] * rl);
    int col = (h & 15) * 64 + nt * 16 + fq * 4;
    *(short4*)&Aout[row * 1024 + col] = sv;
  }
}

// ---------------------------------------------------------------------------
extern "C" void kernel_launch(void* const* d_in, const int* in_sizes, int n_in,
                              void* d_out, int out_size, void* d_ws, size_t ws_size,
                              hipStream_t stream) {
  const float* query = (const float*)d_in[0];
  const float* key   = (const float*)d_in[1];
  const float* value = (const float*)d_in[2];
  const float* mask  = (const float*)d_in[3];
  const float* wts   = (const float*)d_in[4];
  const float* Wq    = (const float*)d_in[5];
  const float* bq    = (const float*)d_in[6];
  const float* Wk    = (const float*)d_in[7];
  const float* bk    = (const float*)d_in[8];
  const float* Wv    = (const float*)d_in[9];
  const float* bv    = (const float*)d_in[10];
  const float* Wo    = (const float*)d_in[11];
  const float* bo    = (const float*)d_in[12];

  char* ws = (char*)d_ws;
  const size_t MB = 1u << 20;
  short* qbf = (short*)(ws + 0);        // 8 MB  (reused as attn out)
  short* kbf = (short*)(ws + 8 * MB);   // 8 MB
  short* vbf = (short*)(ws + 16 * MB);  // 8 MB
  short* Wqb = (short*)(ws + 24 * MB);  // 2 MB
  short* Wkb = (short*)(ws + 26 * MB);
  short* Wvb = (short*)(ws + 28 * MB);
  short* Wob = (short*)(ws + 30 * MB);
  short* Qh  = (short*)(ws + 32 * MB);  // 8 MB [B,N,T,DH]
  short* Kh  = (short*)(ws + 40 * MB);  // 8 MB [B,N,T,DH]
  short* Vth = (short*)(ws + 48 * MB);  // 8 MB [B,N,DH,T]
  short* attnb = qbf;                   // alias: qbf dead after proj_qkv

  cvt_all<<<dim3(2048), dim3(256), 0, stream>>>(query, key, value, Wq, Wk, Wv, Wo,
                                                qbf, kbf, vbf, Wqb, Wkb, Wvb, Wob);
  proj_qkv<<<dim3(16, 16, 3), dim3(256), 0, stream>>>(qbf, kbf, vbf, Wqb, Wkb, Wvb,
                                                      bq, bk, bv, Qh, Kh, Vth);
  attn_kernel<<<dim3(16, 64), dim3(256), 0, stream>>>(Qh, Kh, Vth, wts, mask, attnb);
  gemm_out<<<dim3(16, 16), dim3(512), 0, stream>>>(attnb, Wob, bo, (float*)d_out);
}